// Round 1
// baseline (90.221 us; speedup 1.0000x reference)
//
#include <hip/hip_runtime.h>

typedef __attribute__((ext_vector_type(8))) short short8;
typedef __attribute__((ext_vector_type(8))) unsigned short ushort8;
typedef __attribute__((ext_vector_type(4))) float floatx4;

#define HH 16
#define SS 8192
#define DD 64
#define BSQ 64
#define NBQ 128
#define LOCALW 8
#define LOG2E 1.44269504088896f

__device__ __forceinline__ unsigned short f2bf(float x) {
    unsigned u = __builtin_bit_cast(unsigned, x);
    u += 0x7FFFu + ((u >> 16) & 1u);
    return (unsigned short)(u >> 16);
}

__global__ __launch_bounds__(256, 4) void sparse_attn_kernel(
        const float* __restrict__ qg, const float* __restrict__ kg,
        const float* __restrict__ vg, float* __restrict__ og) {
    __shared__ unsigned short lds_k[64 * 64];    // K[key][d], bf16, XOR-swizzled rows
    __shared__ unsigned short lds_vt[64 * 64];   // V^T[d][key], bf16, XOR-swizzled rows
    __shared__ unsigned short lds_p[4][16 * 64]; // per-wave P[q][key], bf16, swizzled

    const int bx = (int)blockIdx.x;
    const int h = bx >> 7;          // NBQ = 128
    const int i = bx & (NBQ - 1);
    const int tid = (int)threadIdx.x;
    const int w = tid >> 6;
    const int lane = tid & 63;
    const int lp = lane & 15;
    const int g = lane >> 4;

    // ---- load Q fragments (A-layout), fold in sm_scale = 1/8 (exact in bf16) ----
    short8 qf[2];
    {
        const float* qrow = qg + (((h * SS) + i * BSQ + w * 16 + lp) * DD);
        #pragma unroll
        for (int f = 0; f < 2; ++f) {
            const float* p0 = qrow + f * 32 + 8 * g;
            float4 x = *(const float4*)(p0);
            float4 y = *(const float4*)(p0 + 4);
            short8 qq;
            qq[0] = (short)f2bf(x.x * 0.125f);
            qq[1] = (short)f2bf(x.y * 0.125f);
            qq[2] = (short)f2bf(x.z * 0.125f);
            qq[3] = (short)f2bf(x.w * 0.125f);
            qq[4] = (short)f2bf(y.x * 0.125f);
            qq[5] = (short)f2bf(y.y * 0.125f);
            qq[6] = (short)f2bf(y.z * 0.125f);
            qq[7] = (short)f2bf(y.w * 0.125f);
            qf[f] = qq;
        }
    }

    floatx4 acc[4];
    #pragma unroll
    for (int tt = 0; tt < 4; ++tt) acc[tt] = (floatx4)(0.f);
    float m = -1e30f;
    float lsum = 0.f;

    const int nnz = (i < LOCALW) ? (i + 1) : 9;

    for (int t = 0; t < nnz; ++t) {
        const int j = (i < LOCALW) ? t : ((t == 0) ? 0 : (i - 7 + (t - 1)));

        __syncthreads();

        // ---- stage K tile: row-major bf16, swizzled ----
        {
            const float* kb = kg + ((h * SS + j * BSQ) * DD);
            #pragma unroll
            for (int p = 0; p < 4; ++p) {
                const int row = p * 16 + (tid >> 4);
                const int c4 = (tid & 15) * 4;
                float4 x = *(const float4*)(kb + row * DD + c4);
                uint2 pk;
                pk.x = (unsigned)f2bf(x.x) | ((unsigned)f2bf(x.y) << 16);
                pk.y = (unsigned)f2bf(x.z) | ((unsigned)f2bf(x.w) << 16);
                const int e = row * 64 + (c4 ^ ((row & 7) << 3));
                *(uint2*)(&lds_k[e]) = pk;
            }
        }
        // ---- stage V^T tile: lane = d, wave w covers keys w*16..w*16+15 ----
        {
            const float* vb = vg + ((h * SS + j * BSQ) * DD);
            float vals[16];
            #pragma unroll
            for (int kk = 0; kk < 16; ++kk)
                vals[kk] = vb[(w * 16 + kk) * DD + lane];
            ushort8 lo, hi;
            #pragma unroll
            for (int kk = 0; kk < 8; ++kk) lo[kk] = f2bf(vals[kk]);
            #pragma unroll
            for (int kk = 0; kk < 8; ++kk) hi[kk] = f2bf(vals[8 + kk]);
            const int d = lane;
            const int sw = (d & 7) << 3;
            *(ushort8*)(&lds_vt[d * 64 + ((w * 16) ^ sw)]) = lo;
            *(ushort8*)(&lds_vt[d * 64 + ((w * 16 + 8) ^ sw)]) = hi;
        }
        __syncthreads();

        // ---- S^T = K * Q^T  (16 keys x 16 queries per tile, 4 key tiles) ----
        floatx4 st[4];
        #pragma unroll
        for (int kc = 0; kc < 4; ++kc) st[kc] = (floatx4)(0.f);
        const int swl = (lp & 7) << 3;
        #pragma unroll
        for (int kc = 0; kc < 4; ++kc) {
            const int row = kc * 16 + lp;
            const short8 kf0 = *(const short8*)(&lds_k[row * 64 + ((8 * g) ^ swl)]);
            const short8 kf1 = *(const short8*)(&lds_k[row * 64 + ((32 + 8 * g) ^ swl)]);
            st[kc] = __builtin_amdgcn_mfma_f32_16x16x32_bf16(kf0, qf[0], st[kc], 0, 0, 0);
            st[kc] = __builtin_amdgcn_mfma_f32_16x16x32_bf16(kf1, qf[1], st[kc], 0, 0, 0);
        }

        // ---- causal mask (diagonal block only) ----
        if (j == i) {
            #pragma unroll
            for (int kc = 0; kc < 4; ++kc) {
                #pragma unroll
                for (int r = 0; r < 4; ++r) {
                    const int key = kc * 16 + 4 * g + r;
                    if (key > w * 16 + lp) st[kc][r] = -1e30f;
                }
            }
        }

        // ---- online softmax (stats are per q = lp; lanes l, l+16, l+32, l+48 cooperate) ----
        float vmax = -1e30f;
        #pragma unroll
        for (int kc = 0; kc < 4; ++kc) {
            #pragma unroll
            for (int r = 0; r < 4; ++r) vmax = fmaxf(vmax, st[kc][r]);
        }
        vmax = fmaxf(vmax, __shfl_xor(vmax, 16));
        vmax = fmaxf(vmax, __shfl_xor(vmax, 32));
        const float m_new = fmaxf(m, vmax);
        const float alpha = exp2f((m - m_new) * LOG2E);
        float psum = 0.f;
        #pragma unroll
        for (int kc = 0; kc < 4; ++kc) {
            #pragma unroll
            for (int r = 0; r < 4; ++r) {
                const float p = exp2f((st[kc][r] - m_new) * LOG2E);
                st[kc][r] = p;
                psum += p;
            }
        }
        psum += __shfl_xor(psum, 16);
        psum += __shfl_xor(psum, 32);
        lsum = lsum * alpha + psum;
        m = m_new;
        #pragma unroll
        for (int tt = 0; tt < 4; ++tt) acc[tt] *= alpha;

        // ---- write P (bf16) into per-wave LDS: lane holds 4 consecutive keys per tile ----
        unsigned short* pw = lds_p[w];
        #pragma unroll
        for (int kc = 0; kc < 4; ++kc) {
            uint2 pk;
            pk.x = (unsigned)f2bf(st[kc][0]) | ((unsigned)f2bf(st[kc][1]) << 16);
            pk.y = (unsigned)f2bf(st[kc][2]) | ((unsigned)f2bf(st[kc][3]) << 16);
            const int e = lp * 64 + ((kc * 16 + 4 * g) ^ swl);
            *(uint2*)(&pw[e]) = pk;
        }

        // ---- O^T += V^T * P^T ----
        const short8 pf0 = *(const short8*)(&pw[lp * 64 + ((8 * g) ^ swl)]);
        const short8 pf1 = *(const short8*)(&pw[lp * 64 + ((32 + 8 * g) ^ swl)]);
        #pragma unroll
        for (int tt = 0; tt < 4; ++tt) {
            const int row = tt * 16 + lp;
            const short8 vf0 = *(const short8*)(&lds_vt[row * 64 + ((8 * g) ^ swl)]);
            const short8 vf1 = *(const short8*)(&lds_vt[row * 64 + ((32 + 8 * g) ^ swl)]);
            acc[tt] = __builtin_amdgcn_mfma_f32_16x16x32_bf16(vf0, pf0, acc[tt], 0, 0, 0);
            acc[tt] = __builtin_amdgcn_mfma_f32_16x16x32_bf16(vf1, pf1, acc[tt], 0, 0, 0);
        }
    }

    // ---- epilogue: O[q][d] = O^T[d][q] / lsum ----
    const float rn = 1.0f / lsum;
    float* ob = og + ((h * SS + i * BSQ + w * 16 + lp) * DD);
    #pragma unroll
    for (int tt = 0; tt < 4; ++tt) {
        #pragma unroll
        for (int r = 0; r < 4; ++r)
            ob[tt * 16 + 4 * g + r] = acc[tt][r] * rn;
    }
}

extern "C" void kernel_launch(void* const* d_in, const int* in_sizes, int n_in,
                              void* d_out, int out_size, void* d_ws, size_t ws_size,
                              hipStream_t stream) {
    const float* q = (const float*)d_in[0];
    const float* k = (const float*)d_in[1];
    const float* v = (const float*)d_in[2];
    float* out = (float*)d_out;
    dim3 grid(HH * NBQ);   // 2048
    dim3 block(256);
    sparse_attn_kernel<<<grid, block, 0, stream>>>(q, k, v, out);
}

// Round 3
// 67.081 us; speedup vs baseline: 1.3450x; 1.3450x over previous
//
#include <hip/hip_runtime.h>
#include <hip/hip_bf16.h>
#include <string.h>

typedef __attribute__((ext_vector_type(8))) short short8;
typedef __attribute__((ext_vector_type(4))) float floatx4;

#define HH 16
#define SS 8192
#define DD 64
#define NBQ 128
#define LOG2E 1.44269504088896f

__device__ __forceinline__ unsigned pkbf(float a, float b) {
    __hip_bfloat162 h2 = __float22bfloat162_rn(make_float2(a, b));
    unsigned r;
    memcpy(&r, &h2, 4);
    return r;
}

__global__ __launch_bounds__(256, 4) void sparse_attn_kernel(
        const float* __restrict__ qg, const float* __restrict__ kg,
        const float* __restrict__ vg, float* __restrict__ og) {
    __shared__ unsigned short lds_k[2][64 * 64];    // K[key][d] bf16, swizzled
    __shared__ unsigned short lds_vt[2][64 * 64];   // V^T[d][key] bf16, swizzled
    __shared__ unsigned short lds_p[4][16 * 64];    // per-wave P[q][key]

    const int bid = (int)blockIdx.x;
    const int work = (bid & 7) * 256 + (bid >> 3);  // XCD-bijective swizzle (2048%8==0)
    const int h = work >> 7;
    const int i = work & (NBQ - 1);
    const int tid = (int)threadIdx.x;
    const int w = tid >> 6;
    const int lane = tid & 63;
    const int lp = lane & 15;
    const int g = lane >> 4;

    const float* kh = kg + (size_t)h * SS * DD;
    const float* vh = vg + (size_t)h * SS * DD;

    // ---- Q fragments; fold sm_scale*log2(e) so softmax runs in exp2 domain ----
    short8 qf[2];
    {
        const float sc = 0.125f * LOG2E;
        const float* qrow = qg + ((size_t)h * SS + i * 64 + w * 16 + lp) * DD;
        #pragma unroll
        for (int f = 0; f < 2; ++f) {
            const float* p0 = qrow + f * 32 + 8 * g;
            float4 x = *(const float4*)(p0);
            float4 y = *(const float4*)(p0 + 4);
            union { unsigned u[4]; short8 s; } t_;
            t_.u[0] = pkbf(x.x * sc, x.y * sc);
            t_.u[1] = pkbf(x.z * sc, x.w * sc);
            t_.u[2] = pkbf(y.x * sc, y.y * sc);
            t_.u[3] = pkbf(y.z * sc, y.w * sc);
            qf[f] = t_.s;
        }
    }

    floatx4 acc[4];
    #pragma unroll
    for (int tt = 0; tt < 4; ++tt) acc[tt] = (floatx4)(0.f);
    float m = -1e30f;
    float lsum = 0.f;

    const int nnz = (i < 8) ? (i + 1) : 9;

    // staging registers (one tile in flight)
    float4 kreg[4];
    float vreg[16];
    const int krow_sub = tid >> 4;      // 0..15
    const int kc4 = (tid & 15) * 4;

    // ---- prologue: issue loads for tile 0 (j = 0) ----
    {
        const float* kb = kh;
        const float* vb = vh;
        #pragma unroll
        for (int p = 0; p < 4; ++p)
            kreg[p] = *(const float4*)(kb + (p * 16 + krow_sub) * DD + kc4);
        #pragma unroll
        for (int kk = 0; kk < 16; ++kk)
            vreg[kk] = vb[(w * 16 + kk) * DD + lane];
    }

    const int swl = (lp & 7) << 3;

    for (int t = 0; t < nnz; ++t) {
        const int j = (i < 8) ? t : ((t == 0) ? 0 : (i - 8 + t));
        const int buf = t & 1;

        // ---- write staged tile t from regs into LDS buf ----
        #pragma unroll
        for (int p = 0; p < 4; ++p) {
            const int row = p * 16 + krow_sub;
            uint2 pk;
            pk.x = pkbf(kreg[p].x, kreg[p].y);
            pk.y = pkbf(kreg[p].z, kreg[p].w);
            *(uint2*)(&lds_k[buf][row * 64 + (kc4 ^ ((row & 7) << 3))]) = pk;
        }
        {
            const int d = lane;
            const int sw = (d & 7) << 3;
            uint4 A, Bv;
            A.x = pkbf(vreg[0], vreg[1]);   A.y = pkbf(vreg[2], vreg[3]);
            A.z = pkbf(vreg[4], vreg[5]);   A.w = pkbf(vreg[6], vreg[7]);
            Bv.x = pkbf(vreg[8], vreg[9]);  Bv.y = pkbf(vreg[10], vreg[11]);
            Bv.z = pkbf(vreg[12], vreg[13]); Bv.w = pkbf(vreg[14], vreg[15]);
            *(uint4*)(&lds_vt[buf][d * 64 + ((w * 16) ^ sw)]) = A;
            *(uint4*)(&lds_vt[buf][d * 64 + ((w * 16 + 8) ^ sw)]) = Bv;
        }

        // ---- issue loads for tile t+1 (hide latency under compute) ----
        if (t + 1 < nnz) {
            const int jn = (i < 8) ? (t + 1) : (i - 8 + (t + 1));
            const float* kb = kh + jn * (64 * DD);
            const float* vb = vh + jn * (64 * DD);
            #pragma unroll
            for (int p = 0; p < 4; ++p)
                kreg[p] = *(const float4*)(kb + (p * 16 + krow_sub) * DD + kc4);
            #pragma unroll
            for (int kk = 0; kk < 16; ++kk)
                vreg[kk] = vb[(w * 16 + kk) * DD + lane];
        }

        __syncthreads();

        // ---- S^T = K * Q^T (scores already in log2 domain) ----
        floatx4 st[4];
        #pragma unroll
        for (int kc = 0; kc < 4; ++kc) st[kc] = (floatx4)(0.f);
        #pragma unroll
        for (int kc = 0; kc < 4; ++kc) {
            const int row = kc * 16 + lp;
            const short8 kf0 = *(const short8*)(&lds_k[buf][row * 64 + ((8 * g) ^ swl)]);
            const short8 kf1 = *(const short8*)(&lds_k[buf][row * 64 + ((32 + 8 * g) ^ swl)]);
            st[kc] = __builtin_amdgcn_mfma_f32_16x16x32_bf16(kf0, qf[0], st[kc], 0, 0, 0);
            st[kc] = __builtin_amdgcn_mfma_f32_16x16x32_bf16(kf1, qf[1], st[kc], 0, 0, 0);
        }

        // ---- causal mask (diagonal block = last iteration only) ----
        if (j == i) {
            #pragma unroll
            for (int kc = 0; kc < 4; ++kc) {
                #pragma unroll
                for (int r = 0; r < 4; ++r) {
                    const int key = kc * 16 + 4 * g + r;
                    if (key > w * 16 + lp) st[kc][r] = -1e30f;
                }
            }
        }

        // ---- online softmax in exp2 domain (stats per q = lp) ----
        float vmax = -1e30f;
        #pragma unroll
        for (int kc = 0; kc < 4; ++kc) {
            #pragma unroll
            for (int r = 0; r < 4; ++r) vmax = fmaxf(vmax, st[kc][r]);
        }
        vmax = fmaxf(vmax, __shfl_xor(vmax, 16));
        vmax = fmaxf(vmax, __shfl_xor(vmax, 32));
        const float m_new = fmaxf(m, vmax);
        const float alpha = exp2f(m - m_new);
        float psum = 0.f;
        #pragma unroll
        for (int kc = 0; kc < 4; ++kc) {
            #pragma unroll
            for (int r = 0; r < 4; ++r) {
                const float p = exp2f(st[kc][r] - m_new);
                st[kc][r] = p;
                psum += p;
            }
        }
        psum += __shfl_xor(psum, 16);
        psum += __shfl_xor(psum, 32);
        lsum = lsum * alpha + psum;
        m = m_new;
        #pragma unroll
        for (int tt = 0; tt < 4; ++tt) acc[tt] *= alpha;

        // ---- pack P (bf16) into per-wave LDS ----
        unsigned short* pw = lds_p[w];
        #pragma unroll
        for (int kc = 0; kc < 4; ++kc) {
            uint2 pk;
            pk.x = pkbf(st[kc][0], st[kc][1]);
            pk.y = pkbf(st[kc][2], st[kc][3]);
            const int e = lp * 64 + ((kc * 16 + 4 * g) ^ swl);
            *(uint2*)(&pw[e]) = pk;
        }

        // ---- O^T += V^T * P^T ----
        const short8 pf0 = *(const short8*)(&pw[lp * 64 + ((8 * g) ^ swl)]);
        const short8 pf1 = *(const short8*)(&pw[lp * 64 + ((32 + 8 * g) ^ swl)]);
        #pragma unroll
        for (int tt = 0; tt < 4; ++tt) {
            const int row = tt * 16 + lp;
            const short8 vf0 = *(const short8*)(&lds_vt[buf][row * 64 + ((8 * g) ^ swl)]);
            const short8 vf1 = *(const short8*)(&lds_vt[buf][row * 64 + ((32 + 8 * g) ^ swl)]);
            acc[tt] = __builtin_amdgcn_mfma_f32_16x16x32_bf16(vf0, pf0, acc[tt], 0, 0, 0);
            acc[tt] = __builtin_amdgcn_mfma_f32_16x16x32_bf16(vf1, pf1, acc[tt], 0, 0, 0);
        }
    }

    // ---- epilogue: O[q][d] = O^T[d][q] / lsum, float4 stores ----
    const float rn = 1.0f / lsum;
    float* ob = og + ((size_t)h * SS + i * 64 + w * 16 + lp) * DD;
    #pragma unroll
    for (int tt = 0; tt < 4; ++tt) {
        float4 o4;
        o4.x = acc[tt][0] * rn;
        o4.y = acc[tt][1] * rn;
        o4.z = acc[tt][2] * rn;
        o4.w = acc[tt][3] * rn;
        *(float4*)(ob + tt * 16 + 4 * g) = o4;
    }
}

extern "C" void kernel_launch(void* const* d_in, const int* in_sizes, int n_in,
                              void* d_out, int out_size, void* d_ws, size_t ws_size,
                              hipStream_t stream) {
    const float* q = (const float*)d_in[0];
    const float* k = (const float*)d_in[1];
    const float* v = (const float*)d_in[2];
    float* out = (float*)d_out;
    dim3 grid(HH * NBQ);   // 2048
    dim3 block(256);
    sparse_attn_kernel<<<grid, block, 0, stream>>>(q, k, v, out);
}